// Round 15
// baseline (415.994 us; speedup 1.0000x reference)
//
#include <hip/hip_runtime.h>
#include <math.h>

#define N_USERS 50000
#define N_ITEMS 30000
#define N_ENTITIES 80000
#define N_UI (N_USERS + N_ITEMS)
#define D 64
#define N_KG_EDGES 2000000
#define N_INTERACT 1000000
#define N_ADJ 2000000
#define INV_TEMP 5.0f
#define EPS_PD 1e-6f
#define SHIFT 7         // bucket = key >> 7
#define NB 625          // 80000 / 128
#define BKEYS 128
#define BMASK 127
#define EPB 8192        // edges per binA/bhist block
#define BIG 1024        // binA/bhist block size
#define GRID_EP 245     // (2M + EPB-1)/EPB
#define UH_GRID 12500   // N_USERS/4 (256-thr blocks)
#define KG2_GRID 7500   // N_ITEMS/4
#define CVT_GRID 1875   // itmN/4/256

typedef _Float16 f16;
typedef unsigned short u16;
typedef unsigned char u8;
typedef float __attribute__((ext_vector_type(4))) fv4;

__device__ __forceinline__ float4 ld_h4(const f16* p) {
    struct h4 { f16 x, y, z, w; };
    h4 h = *(const h4*)p;
    return make_float4((float)h.x, (float)h.y, (float)h.z, (float)h.w);
}

__device__ __forceinline__ void st_h4(f16* p, float4 v) {
    struct h4 { f16 x, y, z, w; };
    h4 h = {(f16)v.x, (f16)v.y, (f16)v.z, (f16)v.w};
    *(h4*)p = h;
}

__device__ __forceinline__ u16 f16_bits(float v) {
    f16 h = (f16)v;
    return __builtin_bit_cast(u16, h);
}

__device__ __forceinline__ float bits_f16(unsigned b) {
    return (float)__builtin_bit_cast(f16, (u16)b);
}

// non-temporal (evict-early) loads for single-use streams
__device__ __forceinline__ int ldnt_i(const int* p) {
    return __builtin_nontemporal_load(p);
}
__device__ __forceinline__ float ldnt_f(const float* p) {
    return __builtin_nontemporal_load(p);
}
__device__ __forceinline__ float4 ldnt_f4(const float* p) {
    fv4 v = __builtin_nontemporal_load((const fv4*)p);
    return make_float4(v.x, v.y, v.z, v.w);
}

// ==== stage A: bucket histograms (KG + adj) + rowstart binary search ====
__global__ void stageA(const int* __restrict__ kg_ei, const int* __restrict__ adj_r,
                       const int* __restrict__ irows, int* __restrict__ bcntK,
                       int* __restrict__ bcntA, int* __restrict__ rowstart) {
    __shared__ int h[NB];
    int bb = blockIdx.x;
    if (bb < 2 * GRID_EP) {
        bool kg = bb < GRID_EP;
        const int* keys = kg ? kg_ei : adj_r;
        int* bcnt = kg ? bcntK : bcntA;
        int blk = kg ? bb : bb - GRID_EP;
        int n = kg ? N_KG_EDGES : N_ADJ;
        for (int i = threadIdx.x; i < NB; i += BIG) h[i] = 0;
        __syncthreads();
        int e0 = blk * EPB, e1 = min(e0 + EPB, n);
        for (int e = e0 + (int)threadIdx.x; e < e1; e += BIG)
            atomicAdd(&h[ldnt_i(&keys[e]) >> SHIFT], 1);
        __syncthreads();
        for (int i = threadIdx.x; i < NB; i += BIG)
            if (h[i]) atomicAdd(&bcnt[i], h[i]);
    } else {
        int r = (bb - 2 * GRID_EP) * BIG + threadIdx.x;
        if (r > N_USERS) return;
        int lo = 0, hi = N_INTERACT;
        while (lo < hi) {
            int mid = (lo + hi) >> 1;
            if (irows[mid] < r) lo = mid + 1; else hi = mid;
        }
        rowstart[r] = lo;
    }
}

// ==== stage B: scan both bucket arrays (block 0 = KG, block 1 = adj) ====
__global__ void bscan_both(const int* __restrict__ cntK, int* __restrict__ boffK,
                           int* __restrict__ bcurK, const int* __restrict__ cntA,
                           int* __restrict__ boffA, int* __restrict__ bcurA) {
    __shared__ int wp[4];
    __shared__ int carry_s;
    const int* cnt = blockIdx.x ? cntA : cntK;
    int* boff = blockIdx.x ? boffA : boffK;
    int* bcur = blockIdx.x ? bcurA : bcurK;
    int lane = threadIdx.x & 63, wv = threadIdx.x >> 6;
    if (threadIdx.x == 0) { carry_s = 0; boff[0] = 0; }
    __syncthreads();
    for (int base = 0; base < NB; base += 256) {
        int i = base + (int)threadIdx.x;
        int v = (i < NB) ? cnt[i] : 0;
        int x = v;
        #pragma unroll
        for (int o = 1; o < 64; o <<= 1) {
            int t = __shfl_up(x, o, 64);
            if (lane >= o) x += t;
        }
        if (lane == 63) wp[wv] = x;
        __syncthreads();
        int add = carry_s;
        for (int j = 0; j < wv; ++j) add += wp[j];
        int incl = x + add;
        if (i < NB) { boff[i + 1] = incl; bcur[i] = incl - v; }
        __syncthreads();
        if (threadIdx.x == 255) carry_s = incl;
        __syncthreads();
    }
}

// ==== stage C: binA both — LDS-staged block counting sort, line-granular writes ====
__global__ void binA_both(const int* __restrict__ kg_ei, int* __restrict__ bcurK,
                          int* __restrict__ kg_bin, const int* __restrict__ adj_r,
                          const int* __restrict__ adj_c, const float* __restrict__ adj_v,
                          int* __restrict__ bcurA, int* __restrict__ rcP,
                          u8* __restrict__ rcK) {
    __shared__ int stage4[EPB];      // 32 KB
    __shared__ u8 stageK[EPB];       // 8 KB (adj only)
    __shared__ int histS[NB], lstartS[NB], gbaseS[NB];
    __shared__ int wpS[16];
    bool kg = blockIdx.x < GRID_EP;
    int blk = kg ? blockIdx.x : blockIdx.x - GRID_EP;
    int n = kg ? N_KG_EDGES : N_ADJ;
    int* bcur = kg ? bcurK : bcurA;
    const int* keys = kg ? kg_ei : adj_r;
    int tid = threadIdx.x;
    if (tid < NB) histS[tid] = 0;
    __syncthreads();
    int e0 = blk * EPB;
    for (int i = tid; i < EPB; i += BIG) {
        int e = e0 + i;
        if (e < n) atomicAdd(&histS[keys[e] >> SHIFT], 1);
    }
    __syncthreads();
    {
        int lane = tid & 63, wv = tid >> 6;
        int v = (tid < NB) ? histS[tid] : 0;
        int x = v;
        #pragma unroll
        for (int o = 1; o < 64; o <<= 1) {
            int t = __shfl_up(x, o, 64);
            if (lane >= o) x += t;
        }
        if (lane == 63) wpS[wv] = x;
        __syncthreads();
        if (wv == 0) {
            int p = (lane < 16) ? wpS[lane] : 0;
            #pragma unroll
            for (int o = 1; o < 16; o <<= 1) {
                int t = __shfl_up(p, o, 64);
                if (lane >= o) p += t;
            }
            if (lane < 16) wpS[lane] = p;
        }
        __syncthreads();
        int add = (wv > 0) ? wpS[wv - 1] : 0;
        if (tid < NB) {
            lstartS[tid] = (x - v) + add;
            gbaseS[tid] = v ? atomicAdd(&bcur[tid], v) : 0;
            histS[tid] = 0;              // reuse as append cursor
        }
    }
    __syncthreads();
    for (int i = tid; i < EPB; i += BIG) {
        int e = e0 + i;
        if (e >= n) continue;
        int k = keys[e];
        int b = k >> SHIFT;
        int slot = lstartS[b] + atomicAdd(&histS[b], 1);
        if (kg) {
            stage4[slot] = (ldnt_i(&kg_ei[n + e]) << SHIFT) | (k & BMASK);
        } else {
            stage4[slot] = (ldnt_i(&adj_c[e]) << 15) |
                           (int)(f16_bits(ldnt_f(&adj_v[e])) & 0x7FFFu);
            stageK[slot] = (u8)(k & BMASK);
        }
    }
    __syncthreads();
    {
        int lane = tid & 63, wv = tid >> 6;
        for (int b = wv; b < NB; b += 16) {
            int nb = histS[b];
            int src = lstartS[b], dst = gbaseS[b];
            if (kg) {
                for (int j = lane; j < nb; j += 64)
                    kg_bin[dst + j] = stage4[src + j];
            } else {
                for (int j = lane; j < nb; j += 64) {
                    rcP[dst + j] = stage4[src + j];
                    rcK[dst + j] = stageK[src + j];
                }
            }
        }
    }
}

// ==== stage D: binC both — per-bucket CSR rowptr + scatter ====
__global__ void binC_both(const int* __restrict__ boffK, const int* __restrict__ kg_bin,
                          int* __restrict__ tails, int* __restrict__ rowptrK,
                          float* __restrict__ icnt, const int* __restrict__ boffA,
                          const int* __restrict__ rcP, const u8* __restrict__ rcK,
                          int* __restrict__ pair, int* __restrict__ rowptrA) {
    __shared__ int cnt_s[BKEYS];
    __shared__ int cur_s[BKEYS];
    __shared__ int wp2[2];
    bool kg = blockIdx.x < NB;
    int b = kg ? blockIdx.x : blockIdx.x - NB;
    const int* boff = kg ? boffK : boffA;
    int k0 = b << SHIFT;
    int s = boff[b], t = boff[b + 1];
    if (threadIdx.x < BKEYS) cnt_s[threadIdx.x] = 0;
    __syncthreads();
    for (int i = s + (int)threadIdx.x; i < t; i += 256)
        atomicAdd(&cnt_s[kg ? (kg_bin[i] & BMASK) : (int)rcK[i]], 1);
    __syncthreads();
    int lane = threadIdx.x & 63, wv = threadIdx.x >> 6;
    int v = (threadIdx.x < BKEYS) ? cnt_s[threadIdx.x] : 0;
    int x = v;
    #pragma unroll
    for (int o = 1; o < 64; o <<= 1) {
        int tt = __shfl_up(x, o, 64);
        if (lane >= o) x += tt;
    }
    if (threadIdx.x < BKEYS && lane == 63) wp2[wv] = x;
    __syncthreads();
    int add = (wv == 1) ? wp2[0] : 0;
    int excl = s + (x - v) + add;
    if (threadIdx.x < BKEYS) {
        cur_s[threadIdx.x] = excl;
        if (kg) {
            rowptrK[k0 + threadIdx.x] = excl;
            icnt[k0 + threadIdx.x] = 1.0f / fmaxf((float)v, 1.0f);
        } else {
            rowptrA[k0 + threadIdx.x] = excl;
        }
    }
    if (threadIdx.x == 0 && b == NB - 1) {
        if (kg) rowptrK[N_ENTITIES] = t; else rowptrA[N_UI] = t;
    }
    __syncthreads();
    if (kg) {
        for (int i = s + (int)threadIdx.x; i < t; i += 256) {
            int p = kg_bin[i];
            int slot = atomicAdd(&cur_s[p & BMASK], 1);
            tails[slot] = (unsigned)p >> SHIFT;
        }
    } else {
        for (int i = s + (int)threadIdx.x; i < t; i += 256) {
            int slot = atomicAdd(&cur_s[(int)rcK[i]], 1);
            pair[slot] = rcP[i];               // already packed (col<<15 | f16)
        }
    }
}

// ==== KG hop body (fp32): CH-wide chunked gather + normalize + e_res + SNORM ====
template <bool FIRST, int CH>
__device__ __forceinline__ void kg_hop_body(
        int wid, const int* __restrict__ rowptr, const int* __restrict__ tails,
        const float* __restrict__ icnt, const float* __restrict__ Ain,
        float* __restrict__ Aout, float* __restrict__ ER,
        const float* __restrict__ ERI, float* __restrict__ snorm, int nrows) {
    int lane = threadIdx.x & 63;
    int g = lane >> 4, gl = lane & 15;
    if (wid >= nrows) return;
    int s = rowptr[wid], t = rowptr[wid + 1];
    float4 acc = {0.f, 0.f, 0.f, 0.f};
    for (int e = s + g; e < t; e += 4 * CH) {
        int cc[CH];
        float4 rr[CH];
        #pragma unroll
        for (int j = 0; j < CH; ++j) {
            int ej = e + 4 * j;
            cc[j] = (ej < t) ? ldnt_i(&tails[ej]) : 0;
        }
        #pragma unroll
        for (int j = 0; j < CH; ++j) {
            int ej = e + 4 * j;
            rr[j] = make_float4(0.f, 0.f, 0.f, 0.f);
            if (ej < t) rr[j] = *(const float4*)(Ain + (size_t)cc[j] * D + gl * 4);
        }
        #pragma unroll
        for (int j = 0; j < CH; ++j) {
            acc.x += rr[j].x; acc.y += rr[j].y;
            acc.z += rr[j].z; acc.w += rr[j].w;
        }
    }
    acc.x += __shfl_xor(acc.x, 16, 64); acc.x += __shfl_xor(acc.x, 32, 64);
    acc.y += __shfl_xor(acc.y, 16, 64); acc.y += __shfl_xor(acc.y, 32, 64);
    acc.z += __shfl_xor(acc.z, 16, 64); acc.z += __shfl_xor(acc.z, 32, 64);
    acc.w += __shfl_xor(acc.w, 16, 64); acc.w += __shfl_xor(acc.w, 32, 64);
    float ss = acc.x * acc.x + acc.y * acc.y + acc.z * acc.z + acc.w * acc.w;
    ss += __shfl_xor(ss, 1, 64); ss += __shfl_xor(ss, 2, 64);
    ss += __shfl_xor(ss, 4, 64); ss += __shfl_xor(ss, 8, 64);
    float nrm = fmaxf(sqrtf(ss), 1e-12f);
    float inv = 1.0f / nrm;
    if (g == 0) {
        size_t o = (size_t)wid * D + gl * 4;
        float4 ev = {acc.x * inv, acc.y * inv, acc.z * inv, acc.w * inv};
        *(float4*)(Aout + o) = ev;
        if (wid < N_ITEMS) {
            float4 er = FIRST ? *(const float4*)(ERI + o) : *(const float4*)(ER + o);
            er.x += ev.x; er.y += ev.y; er.z += ev.z; er.w += ev.w;
            *(float4*)(ER + o) = er;
            if (gl == 0) snorm[wid] = nrm * icnt[wid];
        }
    }
}

// ==== per-user body: register-cached rows + dot-expansion score + 1-exp softmax ====
template <bool FIRST>
__device__ __forceinline__ void user_hop_body(
        int wid, const float* __restrict__ E, const float* __restrict__ snorm,
        const int* __restrict__ rowstart, const int* __restrict__ cols,
        const float* __restrict__ vals, float* __restrict__ UR,
        const float* __restrict__ URI, f16* __restrict__ XHu) {
    int lane = threadIdx.x & 63;
    int g = lane >> 4, gl = lane & 15;
    if (wid >= N_USERS) return;
    int s = rowstart[wid], t = rowstart[wid + 1];

    float4 mean = {0.f, 0.f, 0.f, 0.f};
    #define UH_LOAD(K)                                                          \
        const int eP##K = s + g + 4 * K;                                        \
        const bool ok##K = eP##K < t;                                           \
        const int cP##K = ok##K ? ldnt_i(&cols[eP##K]) : 0;                     \
        const float snP##K = ok##K ? snorm[cP##K] : 0.f;                        \
        const float vP##K = ok##K ? ldnt_f(&vals[eP##K]) : 0.f;                 \
        float4 rP##K = {0.f, 0.f, 0.f, 0.f};                                    \
        if (ok##K) rP##K = *(const float4*)(E + (size_t)cP##K * D + gl * 4);
    UH_LOAD(0) UH_LOAD(1) UH_LOAD(2) UH_LOAD(3) UH_LOAD(4) UH_LOAD(5)
    #undef UH_LOAD
    #define UH_MEAN(K) {                                                        \
        float w = vP##K * snP##K;                                               \
        mean.x += w * rP##K.x; mean.y += w * rP##K.y;                           \
        mean.z += w * rP##K.z; mean.w += w * rP##K.w; }
    UH_MEAN(0) UH_MEAN(1) UH_MEAN(2) UH_MEAN(3) UH_MEAN(4) UH_MEAN(5)
    #undef UH_MEAN
    for (int e = s + g + 24; e < t; e += 4) {
        int c = ldnt_i(&cols[e]);
        float w = ldnt_f(&vals[e]) * snorm[c];
        float4 r = *(const float4*)(E + (size_t)c * D + gl * 4);
        mean.x += w * r.x; mean.y += w * r.y;
        mean.z += w * r.z; mean.w += w * r.w;
    }
    mean.x += __shfl_xor(mean.x, 16, 64); mean.x += __shfl_xor(mean.x, 32, 64);
    mean.y += __shfl_xor(mean.y, 16, 64); mean.y += __shfl_xor(mean.y, 32, 64);
    mean.z += __shfl_xor(mean.z, 16, 64); mean.z += __shfl_xor(mean.z, 32, 64);
    mean.w += __shfl_xor(mean.w, 16, 64); mean.w += __shfl_xor(mean.w, 32, 64);

    float4 b = {mean.x - EPS_PD, mean.y - EPS_PD, mean.z - EPS_PD, mean.w - EPS_PD};
    float bb = b.x * b.x + b.y * b.y + b.z * b.z + b.w * b.w;
    bb += __shfl_xor(bb, 1, 64); bb += __shfl_xor(bb, 2, 64);
    bb += __shfl_xor(bb, 4, 64); bb += __shfl_xor(bb, 8, 64);

    float m = -INFINITY, denom = 0.f;
    float4 acc = {0.f, 0.f, 0.f, 0.f};
    #define UH_SM(K) if (ok##K) {                                               \
        float dl = rP##K.x * b.x + rP##K.y * b.y + rP##K.z * b.z + rP##K.w * b.w; \
        dl += __shfl_xor(dl, 1, 64); dl += __shfl_xor(dl, 2, 64);               \
        dl += __shfl_xor(dl, 4, 64); dl += __shfl_xor(dl, 8, 64);               \
        float s2 = fmaxf(snP##K * snP##K - 2.f * snP##K * dl + bb, 0.f);        \
        float sc = sqrtf(s2) * INV_TEMP;                                        \
        float dlt = sc - m;                                                     \
        float tt = __expf(fminf(dlt, -dlt));                                    \
        bool up = dlt > 0.f;                                                    \
        float scale = up ? tt : 1.f;                                            \
        float ex = up ? 1.f : tt;                                               \
        if (up) m = sc;                                                         \
        denom = denom * scale + ex;                                             \
        float w = ex * snP##K;                                                  \
        acc.x = acc.x * scale + w * rP##K.x;                                    \
        acc.y = acc.y * scale + w * rP##K.y;                                    \
        acc.z = acc.z * scale + w * rP##K.z;                                    \
        acc.w = acc.w * scale + w * rP##K.w; }
    UH_SM(0) UH_SM(1) UH_SM(2) UH_SM(3) UH_SM(4) UH_SM(5)
    #undef UH_SM
    for (int e = s + g + 24; e < t; e += 4) {
        int c = cols[e];
        float sn = snorm[c];
        float4 r = *(const float4*)(E + (size_t)c * D + gl * 4);
        float dl = r.x * b.x + r.y * b.y + r.z * b.z + r.w * b.w;
        dl += __shfl_xor(dl, 1, 64); dl += __shfl_xor(dl, 2, 64);
        dl += __shfl_xor(dl, 4, 64); dl += __shfl_xor(dl, 8, 64);
        float s2 = fmaxf(sn * sn - 2.f * sn * dl + bb, 0.f);
        float sc = sqrtf(s2) * INV_TEMP;
        float dlt = sc - m;
        float tt = __expf(fminf(dlt, -dlt));
        bool up = dlt > 0.f;
        float scale = up ? tt : 1.f;
        float ex = up ? 1.f : tt;
        if (up) m = sc;
        denom = denom * scale + ex;
        float w = ex * sn;
        acc.x = acc.x * scale + w * r.x;
        acc.y = acc.y * scale + w * r.y;
        acc.z = acc.z * scale + w * r.z;
        acc.w = acc.w * scale + w * r.w;
    }
    float mg = fmaxf(m, __shfl_xor(m, 16, 64));
    mg = fmaxf(mg, __shfl_xor(mg, 32, 64));
    float scl = __expf(fmaxf(m - mg, -88.0f));   // fmax eats NaN from (-inf)-(-inf)
    denom *= scl;
    acc.x *= scl; acc.y *= scl; acc.z *= scl; acc.w *= scl;
    denom += __shfl_xor(denom, 16, 64); denom += __shfl_xor(denom, 32, 64);
    acc.x += __shfl_xor(acc.x, 16, 64); acc.x += __shfl_xor(acc.x, 32, 64);
    acc.y += __shfl_xor(acc.y, 16, 64); acc.y += __shfl_xor(acc.y, 32, 64);
    acc.z += __shfl_xor(acc.z, 16, 64); acc.z += __shfl_xor(acc.z, 32, 64);
    acc.w += __shfl_xor(acc.w, 16, 64); acc.w += __shfl_xor(acc.w, 32, 64);
    float invd = denom > 0.f ? 1.0f / denom : 0.f;
    acc.x *= invd; acc.y *= invd; acc.z *= invd; acc.w *= invd;
    float ss = acc.x * acc.x + acc.y * acc.y + acc.z * acc.z + acc.w * acc.w;
    ss += __shfl_xor(ss, 1, 64); ss += __shfl_xor(ss, 2, 64);
    ss += __shfl_xor(ss, 4, 64); ss += __shfl_xor(ss, 8, 64);
    float inv = 1.0f / fmaxf(sqrtf(ss), 1e-12f);
    if (g == 0) {
        size_t o = (size_t)wid * D + gl * 4;
        float4 u = FIRST ? *(const float4*)(URI + o) : *(const float4*)(UR + o);
        u.x += acc.x * inv; u.y += acc.y * inv; u.z += acc.z * inv; u.w += acc.w * inv;
        *(float4*)(UR + o) = u;
        if (XHu) st_h4(XHu + o, u);
    }
}

// ==== hop-1 over all entities (256-thr blocks, 8-deep gather) ====
__global__ void kg1_kernel(const int* __restrict__ rowptr, const int* __restrict__ tails,
                           const float* __restrict__ icnt, const float* __restrict__ Ain,
                           float* __restrict__ A1, float* __restrict__ ER,
                           const float* __restrict__ ERI, float* __restrict__ sn1) {
    int wid = (blockIdx.x * blockDim.x + threadIdx.x) >> 6;
    kg_hop_body<true, 8>(wid, rowptr, tails, icnt, Ain, A1, ER, ERI, sn1, N_ENTITIES);
}

// ==== mid: user_hop1 (blocks < UH_GRID) || kg_hop2 (rest) — both read A1 ====
__global__ void mid_kernel(const float* __restrict__ A1, const float* __restrict__ sn1,
                           const int* __restrict__ rowstart, const int* __restrict__ cols,
                           const float* __restrict__ vals, float* __restrict__ UR,
                           const float* __restrict__ URI, const int* __restrict__ rowptr,
                           const int* __restrict__ tails, const float* __restrict__ icnt,
                           float* __restrict__ A0I, float* __restrict__ ER,
                           float* __restrict__ sn2) {
    if (blockIdx.x < UH_GRID) {
        int wid = (blockIdx.x * blockDim.x + threadIdx.x) >> 6;
        user_hop_body<true>(wid, A1, sn1, rowstart, cols, vals, UR, URI, nullptr);
    } else {
        int wid = (((blockIdx.x - UH_GRID) * blockDim.x) + threadIdx.x) >> 6;
        kg_hop_body<false, 4>(wid, rowptr, tails, icnt, A1, A0I, ER, nullptr, sn2,
                              N_ITEMS);
    }
}

// ==== fin: user_hop2 (+XH user part) || ER -> XH items cvt ====
__global__ void fin_kernel(const float* __restrict__ A0I, const float* __restrict__ sn2,
                           const int* __restrict__ rowstart, const int* __restrict__ cols,
                           const float* __restrict__ vals, float* __restrict__ UR,
                           f16* __restrict__ XH, const float* __restrict__ ER) {
    if (blockIdx.x < UH_GRID) {
        int wid = (blockIdx.x * blockDim.x + threadIdx.x) >> 6;
        user_hop_body<false>(wid, A0I, sn2, rowstart, cols, vals, UR, nullptr, XH);
    } else {
        int i = (blockIdx.x - UH_GRID) * blockDim.x + threadIdx.x;
        if (i < (N_ITEMS * D) / 4)
            st_h4(XH + (size_t)N_USERS * D + (size_t)i * 4,
                  ldnt_f4(ER + (size_t)i * 4));
    }
}

// ==== adj gather SpMM over fp16 rows, packed 4B (col,val); fp32 epilogues ====
__device__ __forceinline__ const float* xrow32(const float* U, const float* I, int c) {
    return (c < N_USERS) ? (U + (size_t)c * D) : (I + (size_t)(c - N_USERS) * D);
}

template <int MODE>
__global__ void adj_spmm(const int* __restrict__ rowptr, const int* __restrict__ pair,
                         const f16* __restrict__ X, const float* __restrict__ XAU,
                         const float* __restrict__ XAI, f16* __restrict__ Y,
                         float* __restrict__ out) {
    int wid = (blockIdx.x * blockDim.x + threadIdx.x) >> 6;
    int lane = threadIdx.x & 63;
    int g = lane >> 4, gl = lane & 15;
    if (wid >= N_UI) return;
    int s = rowptr[wid], t = rowptr[wid + 1];
    float4 acc = {0.f, 0.f, 0.f, 0.f};
    for (int e = s + g; e < t; e += 16) {
        int e1 = e + 4, e2 = e + 8, e3 = e + 12;
        int p0 = ldnt_i(&pair[e]);
        int p1 = (e1 < t) ? ldnt_i(&pair[e1]) : 0;
        int p2 = (e2 < t) ? ldnt_i(&pair[e2]) : 0;
        int p3 = (e3 < t) ? ldnt_i(&pair[e3]) : 0;
        float4 r0 = ld_h4(X + (size_t)((unsigned)p0 >> 15) * D + gl * 4);
        float4 r1 = {0.f, 0.f, 0.f, 0.f};
        float4 r2 = {0.f, 0.f, 0.f, 0.f};
        float4 r3 = {0.f, 0.f, 0.f, 0.f};
        if (e1 < t) r1 = ld_h4(X + (size_t)((unsigned)p1 >> 15) * D + gl * 4);
        if (e2 < t) r2 = ld_h4(X + (size_t)((unsigned)p2 >> 15) * D + gl * 4);
        if (e3 < t) r3 = ld_h4(X + (size_t)((unsigned)p3 >> 15) * D + gl * 4);
        float v0 = bits_f16(p0 & 0x7FFF), v1 = bits_f16(p1 & 0x7FFF);
        float v2 = bits_f16(p2 & 0x7FFF), v3 = bits_f16(p3 & 0x7FFF);
        acc.x += (v0 * r0.x + v1 * r1.x) + (v2 * r2.x + v3 * r3.x);
        acc.y += (v0 * r0.y + v1 * r1.y) + (v2 * r2.y + v3 * r3.y);
        acc.z += (v0 * r0.z + v1 * r1.z) + (v2 * r2.z + v3 * r3.z);
        acc.w += (v0 * r0.w + v1 * r1.w) + (v2 * r2.w + v3 * r3.w);
    }
    acc.x += __shfl_xor(acc.x, 16, 64); acc.x += __shfl_xor(acc.x, 32, 64);
    acc.y += __shfl_xor(acc.y, 16, 64); acc.y += __shfl_xor(acc.y, 32, 64);
    acc.z += __shfl_xor(acc.z, 16, 64); acc.z += __shfl_xor(acc.z, 32, 64);
    acc.w += __shfl_xor(acc.w, 16, 64); acc.w += __shfl_xor(acc.w, 32, 64);
    if (g == 0) {
        size_t o = (size_t)wid * D + gl * 4;
        if (MODE == 0) {
            st_h4(Y + o, acc);
            const float4 xa = *(const float4*)(xrow32(XAU, XAI, wid) + gl * 4);
            float4 ov = {xa.x + acc.x, xa.y + acc.y, xa.z + acc.z, xa.w + acc.w};
            *(float4*)(out + o) = ov;
        } else {
            float4 ov = *(const float4*)(out + o);
            ov.x = (ov.x + acc.x) * (1.0f / 3.0f);
            ov.y = (ov.y + acc.y) * (1.0f / 3.0f);
            ov.z = (ov.z + acc.z) * (1.0f / 3.0f);
            ov.w = (ov.w + acc.w) * (1.0f / 3.0f);
            *(float4*)(out + o) = ov;
        }
    }
}

extern "C" void kernel_launch(void* const* d_in, const int* in_sizes, int n_in,
                              void* d_out, int out_size, void* d_ws, size_t ws_size,
                              hipStream_t stream) {
    const float* all_embed     = (const float*)d_in[0];
    const float* interact_vals = (const float*)d_in[1];
    const float* adj_vals      = (const float*)d_in[2];
    const int*   edge_index    = (const int*)d_in[3];
    // d_in[4] = edge_type (unused)
    const int*   interact_rows = (const int*)d_in[5];
    const int*   interact_cols = (const int*)d_in[6];
    const int*   adj_rows      = (const int*)d_in[7];
    const int*   adj_cols      = (const int*)d_in[8];
    float* out = (float*)d_out;

    const size_t usrN = (size_t)N_USERS * D;      // 3,200,000
    const size_t itmN = (size_t)N_ITEMS * D;      // 1,920,000
    const size_t entN = (size_t)N_ENTITIES * D;   // 5,120,000

    float* cur = (float*)d_ws;
    float* UR  = cur; cur += usrN;                // u_res (KG_BIN overlays pre-mid)
    float* ER  = cur; cur += itmN;                // e_res items
    float* A0I = cur; cur += itmN;                // hop-2 output, items only
    float* A1  = cur; cur += entN;                // hop-1 output (rc pre / XH,X1H post)
    int*  KG_TAIL  = (int*)cur; cur += N_KG_EDGES;
    int*  ADJ_PAIR = (int*)cur; cur += N_ADJ;     // packed 4B (col<<15 | f16 bits)
    float* ICNT   = cur; cur += N_ENTITIES;
    float* SNORM1 = cur; cur += N_ITEMS + 16;
    float* SNORM2 = cur; cur += N_ITEMS + 16;
    int* KG_ROWPTR  = (int*)cur;                   // N_ENTITIES+1 (+pad)
    int* ADJ_ROWPTR = KG_ROWPTR + N_ENTITIES + 2;  // N_UI+1 (+pad)
    int* BCNT_K     = ADJ_ROWPTR + N_UI + 2;       // NB (K/A contiguous for memset)
    int* BCNT_A     = BCNT_K + NB;                 // NB
    int* BOFF_K     = BCNT_A + NB;                 // NB+1
    int* BOFF_A     = BOFF_K + NB + 1;             // NB+1
    int* BCUR_K     = BOFF_A + NB + 1;             // NB
    int* BCUR_A     = BCUR_K + NB;                 // NB
    int* ROWSTART   = BCUR_A + NB;                 // N_USERS+1

    // overlays (timeline-disjoint)
    int* KG_BIN = (int*)UR;                        // binA..binC, before user_hop1 writes UR
    int* ADJ_RCP = (int*)A1;                       // binA..binC, before kg1 writes A1
    u8*  ADJ_RCK = (u8*)(A1 + N_ADJ);              // 2 MB, after RCP's 8 MB
    f16* XH  = (f16*)A1;                           // after mid (A1 dead post kg_hop2)
    f16* X1H = XH + (size_t)N_UI * D;

    // ---- CSR builds (KG + adj fused stage-wise) ----
    hipMemsetAsync(BCNT_K, 0, 2 * NB * sizeof(int), stream);
    stageA<<<2 * GRID_EP + 49, BIG, 0, stream>>>(edge_index, adj_rows, interact_rows,
                                                 BCNT_K, BCNT_A, ROWSTART);
    bscan_both<<<2, 256, 0, stream>>>(BCNT_K, BOFF_K, BCUR_K, BCNT_A, BOFF_A, BCUR_A);
    binA_both<<<2 * GRID_EP, BIG, 0, stream>>>(edge_index, BCUR_K, KG_BIN, adj_rows,
                                               adj_cols, adj_vals, BCUR_A,
                                               ADJ_RCP, ADJ_RCK);
    binC_both<<<2 * NB, 256, 0, stream>>>(BOFF_K, KG_BIN, KG_TAIL, KG_ROWPTR, ICNT,
                                          BOFF_A, ADJ_RCP, ADJ_RCK, ADJ_PAIR,
                                          ADJ_ROWPTR);

    // ---- KG hops: kg1 -> (user1 || kg2) -> (user2 || cvt-items) ----
    kg1_kernel<<<N_ENTITIES / 4, 256, 0, stream>>>(KG_ROWPTR, KG_TAIL, ICNT,
                                                   all_embed + usrN, A1, ER,
                                                   all_embed + usrN, SNORM1);
    mid_kernel<<<UH_GRID + KG2_GRID, 256, 0, stream>>>(A1, SNORM1, ROWSTART,
                                                       interact_cols, interact_vals,
                                                       UR, all_embed, KG_ROWPTR, KG_TAIL,
                                                       ICNT, A0I, ER, SNORM2);
    fin_kernel<<<UH_GRID + CVT_GRID, 256, 0, stream>>>(A0I, SNORM2, ROWSTART,
                                                       interact_cols, interact_vals,
                                                       UR, XH, ER);

    // ---- LGCN: x1 = adj@x -> X1H(f16), out = x + x1; out = (out + adj@x1)/3 ----
    adj_spmm<0><<<N_UI / 4, 256, 0, stream>>>(ADJ_ROWPTR, ADJ_PAIR, XH, UR, ER, X1H, out);
    adj_spmm<1><<<N_UI / 4, 256, 0, stream>>>(ADJ_ROWPTR, ADJ_PAIR, X1H, nullptr, nullptr,
                                              nullptr, out);
}

// Round 16
// 375.162 us; speedup vs baseline: 1.1088x; 1.1088x over previous
//
#include <hip/hip_runtime.h>
#include <math.h>

#define N_USERS 50000
#define N_ITEMS 30000
#define N_ENTITIES 80000
#define N_UI (N_USERS + N_ITEMS)
#define D 64
#define N_KG_EDGES 2000000
#define N_INTERACT 1000000
#define N_ADJ 2000000
#define INV_TEMP 5.0f
#define EPS_PD 1e-6f
#define SHIFT 7         // bucket = key >> 7
#define NB 625          // 80000 / 128
#define BKEYS 128
#define BMASK 127
#define EPB 8192        // edges per binA/bhist block
#define BIG 1024        // binA/bhist block size
#define GRID_EP 245     // (2M + EPB-1)/EPB
#define UH_GRID 12500   // N_USERS/4 (256-thr blocks)
#define KG2_GRID 7500   // N_ITEMS/4
#define CVT_GRID 1875   // itmN/4/256

typedef _Float16 f16;
typedef unsigned short u16;
typedef unsigned char u8;

__device__ __forceinline__ float4 ld_h4(const f16* p) {
    struct h4 { f16 x, y, z, w; };
    h4 h = *(const h4*)p;
    return make_float4((float)h.x, (float)h.y, (float)h.z, (float)h.w);
}

__device__ __forceinline__ void st_h4(f16* p, float4 v) {
    struct h4 { f16 x, y, z, w; };
    h4 h = {(f16)v.x, (f16)v.y, (f16)v.z, (f16)v.w};
    *(h4*)p = h;
}

__device__ __forceinline__ u16 f16_bits(float v) {
    f16 h = (f16)v;
    return __builtin_bit_cast(u16, h);
}

__device__ __forceinline__ float bits_f16(unsigned b) {
    return (float)__builtin_bit_cast(f16, (u16)b);
}

// ==== stage A: bucket histograms (KG + adj) + rowstart binary search ====
__global__ void stageA(const int* __restrict__ kg_ei, const int* __restrict__ adj_r,
                       const int* __restrict__ irows, int* __restrict__ bcntK,
                       int* __restrict__ bcntA, int* __restrict__ rowstart) {
    __shared__ int h[NB];
    int bb = blockIdx.x;
    if (bb < 2 * GRID_EP) {
        bool kg = bb < GRID_EP;
        const int* keys = kg ? kg_ei : adj_r;
        int* bcnt = kg ? bcntK : bcntA;
        int blk = kg ? bb : bb - GRID_EP;
        int n = kg ? N_KG_EDGES : N_ADJ;
        for (int i = threadIdx.x; i < NB; i += BIG) h[i] = 0;
        __syncthreads();
        int e0 = blk * EPB, e1 = min(e0 + EPB, n);
        for (int e = e0 + (int)threadIdx.x; e < e1; e += BIG)
            atomicAdd(&h[keys[e] >> SHIFT], 1);
        __syncthreads();
        for (int i = threadIdx.x; i < NB; i += BIG)
            if (h[i]) atomicAdd(&bcnt[i], h[i]);
    } else {
        int r = (bb - 2 * GRID_EP) * BIG + threadIdx.x;
        if (r > N_USERS) return;
        int lo = 0, hi = N_INTERACT;
        while (lo < hi) {
            int mid = (lo + hi) >> 1;
            if (irows[mid] < r) lo = mid + 1; else hi = mid;
        }
        rowstart[r] = lo;
    }
}

// ==== stage B: scan both bucket arrays (block 0 = KG, block 1 = adj) ====
__global__ void bscan_both(const int* __restrict__ cntK, int* __restrict__ boffK,
                           int* __restrict__ bcurK, const int* __restrict__ cntA,
                           int* __restrict__ boffA, int* __restrict__ bcurA) {
    __shared__ int wp[4];
    __shared__ int carry_s;
    const int* cnt = blockIdx.x ? cntA : cntK;
    int* boff = blockIdx.x ? boffA : boffK;
    int* bcur = blockIdx.x ? bcurA : bcurK;
    int lane = threadIdx.x & 63, wv = threadIdx.x >> 6;
    if (threadIdx.x == 0) { carry_s = 0; boff[0] = 0; }
    __syncthreads();
    for (int base = 0; base < NB; base += 256) {
        int i = base + (int)threadIdx.x;
        int v = (i < NB) ? cnt[i] : 0;
        int x = v;
        #pragma unroll
        for (int o = 1; o < 64; o <<= 1) {
            int t = __shfl_up(x, o, 64);
            if (lane >= o) x += t;
        }
        if (lane == 63) wp[wv] = x;
        __syncthreads();
        int add = carry_s;
        for (int j = 0; j < wv; ++j) add += wp[j];
        int incl = x + add;
        if (i < NB) { boff[i + 1] = incl; bcur[i] = incl - v; }
        __syncthreads();
        if (threadIdx.x == 255) carry_s = incl;
        __syncthreads();
    }
}

// ==== stage C: binA both — LDS-staged block counting sort, line-granular writes ====
// KG record: (tail<<7 | key) 4B.  adj record: packed pair (col<<15 | f16val) 4B + key u8.
__global__ void binA_both(const int* __restrict__ kg_ei, int* __restrict__ bcurK,
                          int* __restrict__ kg_bin, const int* __restrict__ adj_r,
                          const int* __restrict__ adj_c, const float* __restrict__ adj_v,
                          int* __restrict__ bcurA, int* __restrict__ rcP,
                          u8* __restrict__ rcK) {
    __shared__ int stage4[EPB];      // 32 KB
    __shared__ u8 stageK[EPB];       // 8 KB (adj only)
    __shared__ int histS[NB], lstartS[NB], gbaseS[NB];
    __shared__ int wpS[16];
    bool kg = blockIdx.x < GRID_EP;
    int blk = kg ? blockIdx.x : blockIdx.x - GRID_EP;
    int n = kg ? N_KG_EDGES : N_ADJ;
    int* bcur = kg ? bcurK : bcurA;
    const int* keys = kg ? kg_ei : adj_r;
    int tid = threadIdx.x;
    if (tid < NB) histS[tid] = 0;
    __syncthreads();
    int e0 = blk * EPB;
    for (int i = tid; i < EPB; i += BIG) {
        int e = e0 + i;
        if (e < n) atomicAdd(&histS[keys[e] >> SHIFT], 1);
    }
    __syncthreads();
    // block-level exclusive scan -> lstart; global run reservation -> gbase
    {
        int lane = tid & 63, wv = tid >> 6;
        int v = (tid < NB) ? histS[tid] : 0;
        int x = v;
        #pragma unroll
        for (int o = 1; o < 64; o <<= 1) {
            int t = __shfl_up(x, o, 64);
            if (lane >= o) x += t;
        }
        if (lane == 63) wpS[wv] = x;
        __syncthreads();
        if (wv == 0) {
            int p = (lane < 16) ? wpS[lane] : 0;
            #pragma unroll
            for (int o = 1; o < 16; o <<= 1) {
                int t = __shfl_up(p, o, 64);
                if (lane >= o) p += t;
            }
            if (lane < 16) wpS[lane] = p;
        }
        __syncthreads();
        int add = (wv > 0) ? wpS[wv - 1] : 0;
        if (tid < NB) {
            lstartS[tid] = (x - v) + add;
            gbaseS[tid] = v ? atomicAdd(&bcur[tid], v) : 0;
            histS[tid] = 0;              // reuse as append cursor
        }
    }
    __syncthreads();
    // staging: scatter records into LDS in bucket order
    for (int i = tid; i < EPB; i += BIG) {
        int e = e0 + i;
        if (e >= n) continue;
        int k = keys[e];
        int b = k >> SHIFT;
        int slot = lstartS[b] + atomicAdd(&histS[b], 1);
        if (kg) {
            stage4[slot] = (kg_ei[n + e] << SHIFT) | (k & BMASK);
        } else {
            stage4[slot] = (adj_c[e] << 15) | (int)(f16_bits(adj_v[e]) & 0x7FFFu);
            stageK[slot] = (u8)(k & BMASK);
        }
    }
    __syncthreads();
    // bulk write: one wave per bucket run, back-to-back stores -> full lines
    {
        int lane = tid & 63, wv = tid >> 6;
        for (int b = wv; b < NB; b += 16) {
            int nb = histS[b];
            int src = lstartS[b], dst = gbaseS[b];
            if (kg) {
                for (int j = lane; j < nb; j += 64)
                    kg_bin[dst + j] = stage4[src + j];
            } else {
                for (int j = lane; j < nb; j += 64) {
                    rcP[dst + j] = stage4[src + j];
                    rcK[dst + j] = stageK[src + j];
                }
            }
        }
    }
}

// ==== stage D: binC both — per-bucket CSR rowptr + scatter ====
__global__ void binC_both(const int* __restrict__ boffK, const int* __restrict__ kg_bin,
                          int* __restrict__ tails, int* __restrict__ rowptrK,
                          float* __restrict__ icnt, const int* __restrict__ boffA,
                          const int* __restrict__ rcP, const u8* __restrict__ rcK,
                          int* __restrict__ pair, int* __restrict__ rowptrA) {
    __shared__ int cnt_s[BKEYS];
    __shared__ int cur_s[BKEYS];
    __shared__ int wp2[2];
    bool kg = blockIdx.x < NB;
    int b = kg ? blockIdx.x : blockIdx.x - NB;
    const int* boff = kg ? boffK : boffA;
    int k0 = b << SHIFT;
    int s = boff[b], t = boff[b + 1];
    if (threadIdx.x < BKEYS) cnt_s[threadIdx.x] = 0;
    __syncthreads();
    for (int i = s + (int)threadIdx.x; i < t; i += 256)
        atomicAdd(&cnt_s[kg ? (kg_bin[i] & BMASK) : (int)rcK[i]], 1);
    __syncthreads();
    int lane = threadIdx.x & 63, wv = threadIdx.x >> 6;
    int v = (threadIdx.x < BKEYS) ? cnt_s[threadIdx.x] : 0;
    int x = v;
    #pragma unroll
    for (int o = 1; o < 64; o <<= 1) {
        int tt = __shfl_up(x, o, 64);
        if (lane >= o) x += tt;
    }
    if (threadIdx.x < BKEYS && lane == 63) wp2[wv] = x;
    __syncthreads();
    int add = (wv == 1) ? wp2[0] : 0;
    int excl = s + (x - v) + add;
    if (threadIdx.x < BKEYS) {
        cur_s[threadIdx.x] = excl;
        if (kg) {
            rowptrK[k0 + threadIdx.x] = excl;
            icnt[k0 + threadIdx.x] = 1.0f / fmaxf((float)v, 1.0f);
        } else {
            rowptrA[k0 + threadIdx.x] = excl;
        }
    }
    if (threadIdx.x == 0 && b == NB - 1) {
        if (kg) rowptrK[N_ENTITIES] = t; else rowptrA[N_UI] = t;
    }
    __syncthreads();
    if (kg) {
        for (int i = s + (int)threadIdx.x; i < t; i += 256) {
            int p = kg_bin[i];
            int slot = atomicAdd(&cur_s[p & BMASK], 1);
            tails[slot] = (unsigned)p >> SHIFT;
        }
    } else {
        for (int i = s + (int)threadIdx.x; i < t; i += 256) {
            int slot = atomicAdd(&cur_s[(int)rcK[i]], 1);
            pair[slot] = rcP[i];               // already packed (col<<15 | f16)
        }
    }
}

// ==== KG hop body (fp32): 4-wide chunked gather + normalize + e_res + SNORM ====
template <bool FIRST>
__device__ __forceinline__ void kg_hop_body(
        int wid, const int* __restrict__ rowptr, const int* __restrict__ tails,
        const float* __restrict__ icnt, const float* __restrict__ Ain,
        float* __restrict__ Aout, float* __restrict__ ER,
        const float* __restrict__ ERI, float* __restrict__ snorm, int nrows) {
    int lane = threadIdx.x & 63;
    int g = lane >> 4, gl = lane & 15;
    if (wid >= nrows) return;
    int s = rowptr[wid], t = rowptr[wid + 1];
    float4 acc = {0.f, 0.f, 0.f, 0.f};
    for (int e = s + g; e < t; e += 16) {
        int e1 = e + 4, e2 = e + 8, e3 = e + 12;
        int c0 = tails[e];
        int c1 = (e1 < t) ? tails[e1] : 0;
        int c2 = (e2 < t) ? tails[e2] : 0;
        int c3 = (e3 < t) ? tails[e3] : 0;
        float4 r0 = *(const float4*)(Ain + (size_t)c0 * D + gl * 4);
        float4 r1 = {0.f, 0.f, 0.f, 0.f};
        float4 r2 = {0.f, 0.f, 0.f, 0.f};
        float4 r3 = {0.f, 0.f, 0.f, 0.f};
        if (e1 < t) r1 = *(const float4*)(Ain + (size_t)c1 * D + gl * 4);
        if (e2 < t) r2 = *(const float4*)(Ain + (size_t)c2 * D + gl * 4);
        if (e3 < t) r3 = *(const float4*)(Ain + (size_t)c3 * D + gl * 4);
        acc.x += (r0.x + r1.x) + (r2.x + r3.x);
        acc.y += (r0.y + r1.y) + (r2.y + r3.y);
        acc.z += (r0.z + r1.z) + (r2.z + r3.z);
        acc.w += (r0.w + r1.w) + (r2.w + r3.w);
    }
    acc.x += __shfl_xor(acc.x, 16, 64); acc.x += __shfl_xor(acc.x, 32, 64);
    acc.y += __shfl_xor(acc.y, 16, 64); acc.y += __shfl_xor(acc.y, 32, 64);
    acc.z += __shfl_xor(acc.z, 16, 64); acc.z += __shfl_xor(acc.z, 32, 64);
    acc.w += __shfl_xor(acc.w, 16, 64); acc.w += __shfl_xor(acc.w, 32, 64);
    float ss = acc.x * acc.x + acc.y * acc.y + acc.z * acc.z + acc.w * acc.w;
    ss += __shfl_xor(ss, 1, 64); ss += __shfl_xor(ss, 2, 64);
    ss += __shfl_xor(ss, 4, 64); ss += __shfl_xor(ss, 8, 64);
    float nrm = fmaxf(sqrtf(ss), 1e-12f);
    float inv = 1.0f / nrm;
    if (g == 0) {
        size_t o = (size_t)wid * D + gl * 4;
        float4 ev = {acc.x * inv, acc.y * inv, acc.z * inv, acc.w * inv};
        *(float4*)(Aout + o) = ev;
        if (wid < N_ITEMS) {
            float4 er = FIRST ? *(const float4*)(ERI + o) : *(const float4*)(ER + o);
            er.x += ev.x; er.y += ev.y; er.z += ev.z; er.w += ev.w;
            *(float4*)(ER + o) = er;
            if (gl == 0) snorm[wid] = nrm * icnt[wid];
        }
    }
}

// ==== per-user body: register-cached rows + dot-expansion score + 1-exp softmax ====
template <bool FIRST>
__device__ __forceinline__ void user_hop_body(
        int wid, const float* __restrict__ E, const float* __restrict__ snorm,
        const int* __restrict__ rowstart, const int* __restrict__ cols,
        const float* __restrict__ vals, float* __restrict__ UR,
        const float* __restrict__ URI, f16* __restrict__ XHu) {
    int lane = threadIdx.x & 63;
    int g = lane >> 4, gl = lane & 15;
    if (wid >= N_USERS) return;
    int s = rowstart[wid], t = rowstart[wid + 1];

    float4 mean = {0.f, 0.f, 0.f, 0.f};
    #define UH_LOAD(K)                                                          \
        const int eP##K = s + g + 4 * K;                                        \
        const bool ok##K = eP##K < t;                                           \
        const int cP##K = ok##K ? cols[eP##K] : 0;                              \
        const float snP##K = ok##K ? snorm[cP##K] : 0.f;                        \
        const float vP##K = ok##K ? vals[eP##K] : 0.f;                          \
        float4 rP##K = {0.f, 0.f, 0.f, 0.f};                                    \
        if (ok##K) rP##K = *(const float4*)(E + (size_t)cP##K * D + gl * 4);
    UH_LOAD(0) UH_LOAD(1) UH_LOAD(2) UH_LOAD(3) UH_LOAD(4) UH_LOAD(5)
    #undef UH_LOAD
    #define UH_MEAN(K) {                                                        \
        float w = vP##K * snP##K;                                               \
        mean.x += w * rP##K.x; mean.y += w * rP##K.y;                           \
        mean.z += w * rP##K.z; mean.w += w * rP##K.w; }
    UH_MEAN(0) UH_MEAN(1) UH_MEAN(2) UH_MEAN(3) UH_MEAN(4) UH_MEAN(5)
    #undef UH_MEAN
    for (int e = s + g + 24; e < t; e += 4) {
        int c = cols[e];
        float w = vals[e] * snorm[c];
        float4 r = *(const float4*)(E + (size_t)c * D + gl * 4);
        mean.x += w * r.x; mean.y += w * r.y;
        mean.z += w * r.z; mean.w += w * r.w;
    }
    mean.x += __shfl_xor(mean.x, 16, 64); mean.x += __shfl_xor(mean.x, 32, 64);
    mean.y += __shfl_xor(mean.y, 16, 64); mean.y += __shfl_xor(mean.y, 32, 64);
    mean.z += __shfl_xor(mean.z, 16, 64); mean.z += __shfl_xor(mean.z, 32, 64);
    mean.w += __shfl_xor(mean.w, 16, 64); mean.w += __shfl_xor(mean.w, 32, 64);

    float4 b = {mean.x - EPS_PD, mean.y - EPS_PD, mean.z - EPS_PD, mean.w - EPS_PD};
    float bb = b.x * b.x + b.y * b.y + b.z * b.z + b.w * b.w;
    bb += __shfl_xor(bb, 1, 64); bb += __shfl_xor(bb, 2, 64);
    bb += __shfl_xor(bb, 4, 64); bb += __shfl_xor(bb, 8, 64);

    float m = -INFINITY, denom = 0.f;
    float4 acc = {0.f, 0.f, 0.f, 0.f};
    #define UH_SM(K) if (ok##K) {                                               \
        float dl = rP##K.x * b.x + rP##K.y * b.y + rP##K.z * b.z + rP##K.w * b.w; \
        dl += __shfl_xor(dl, 1, 64); dl += __shfl_xor(dl, 2, 64);               \
        dl += __shfl_xor(dl, 4, 64); dl += __shfl_xor(dl, 8, 64);               \
        float s2 = fmaxf(snP##K * snP##K - 2.f * snP##K * dl + bb, 0.f);        \
        float sc = sqrtf(s2) * INV_TEMP;                                        \
        float dlt = sc - m;                                                     \
        float tt = __expf(fminf(dlt, -dlt));                                    \
        bool up = dlt > 0.f;                                                    \
        float scale = up ? tt : 1.f;                                            \
        float ex = up ? 1.f : tt;                                               \
        if (up) m = sc;                                                         \
        denom = denom * scale + ex;                                             \
        float w = ex * snP##K;                                                  \
        acc.x = acc.x * scale + w * rP##K.x;                                    \
        acc.y = acc.y * scale + w * rP##K.y;                                    \
        acc.z = acc.z * scale + w * rP##K.z;                                    \
        acc.w = acc.w * scale + w * rP##K.w; }
    UH_SM(0) UH_SM(1) UH_SM(2) UH_SM(3) UH_SM(4) UH_SM(5)
    #undef UH_SM
    for (int e = s + g + 24; e < t; e += 4) {
        int c = cols[e];
        float sn = snorm[c];
        float4 r = *(const float4*)(E + (size_t)c * D + gl * 4);
        float dl = r.x * b.x + r.y * b.y + r.z * b.z + r.w * b.w;
        dl += __shfl_xor(dl, 1, 64); dl += __shfl_xor(dl, 2, 64);
        dl += __shfl_xor(dl, 4, 64); dl += __shfl_xor(dl, 8, 64);
        float s2 = fmaxf(sn * sn - 2.f * sn * dl + bb, 0.f);
        float sc = sqrtf(s2) * INV_TEMP;
        float dlt = sc - m;
        float tt = __expf(fminf(dlt, -dlt));
        bool up = dlt > 0.f;
        float scale = up ? tt : 1.f;
        float ex = up ? 1.f : tt;
        if (up) m = sc;
        denom = denom * scale + ex;
        float w = ex * sn;
        acc.x = acc.x * scale + w * r.x;
        acc.y = acc.y * scale + w * r.y;
        acc.z = acc.z * scale + w * r.z;
        acc.w = acc.w * scale + w * r.w;
    }
    float mg = fmaxf(m, __shfl_xor(m, 16, 64));
    mg = fmaxf(mg, __shfl_xor(mg, 32, 64));
    float scl = __expf(fmaxf(m - mg, -88.0f));   // fmax eats NaN from (-inf)-(-inf)
    denom *= scl;
    acc.x *= scl; acc.y *= scl; acc.z *= scl; acc.w *= scl;
    denom += __shfl_xor(denom, 16, 64); denom += __shfl_xor(denom, 32, 64);
    acc.x += __shfl_xor(acc.x, 16, 64); acc.x += __shfl_xor(acc.x, 32, 64);
    acc.y += __shfl_xor(acc.y, 16, 64); acc.y += __shfl_xor(acc.y, 32, 64);
    acc.z += __shfl_xor(acc.z, 16, 64); acc.z += __shfl_xor(acc.z, 32, 64);
    acc.w += __shfl_xor(acc.w, 16, 64); acc.w += __shfl_xor(acc.w, 32, 64);
    float invd = denom > 0.f ? 1.0f / denom : 0.f;
    acc.x *= invd; acc.y *= invd; acc.z *= invd; acc.w *= invd;
    float ss = acc.x * acc.x + acc.y * acc.y + acc.z * acc.z + acc.w * acc.w;
    ss += __shfl_xor(ss, 1, 64); ss += __shfl_xor(ss, 2, 64);
    ss += __shfl_xor(ss, 4, 64); ss += __shfl_xor(ss, 8, 64);
    float inv = 1.0f / fmaxf(sqrtf(ss), 1e-12f);
    if (g == 0) {
        size_t o = (size_t)wid * D + gl * 4;
        float4 u = FIRST ? *(const float4*)(URI + o) : *(const float4*)(UR + o);
        u.x += acc.x * inv; u.y += acc.y * inv; u.z += acc.z * inv; u.w += acc.w * inv;
        *(float4*)(UR + o) = u;
        if (XHu) st_h4(XHu + o, u);
    }
}

// ==== hop-1 over all entities (256-thr blocks) ====
__global__ void kg1_kernel(const int* __restrict__ rowptr, const int* __restrict__ tails,
                           const float* __restrict__ icnt, const float* __restrict__ Ain,
                           float* __restrict__ A1, float* __restrict__ ER,
                           const float* __restrict__ ERI, float* __restrict__ sn1) {
    int wid = (blockIdx.x * blockDim.x + threadIdx.x) >> 6;
    kg_hop_body<true>(wid, rowptr, tails, icnt, Ain, A1, ER, ERI, sn1, N_ENTITIES);
}

// ==== mid: user_hop1 (blocks < UH_GRID) || kg_hop2 (rest) — both read A1 ====
__global__ void mid_kernel(const float* __restrict__ A1, const float* __restrict__ sn1,
                           const int* __restrict__ rowstart, const int* __restrict__ cols,
                           const float* __restrict__ vals, float* __restrict__ UR,
                           const float* __restrict__ URI, const int* __restrict__ rowptr,
                           const int* __restrict__ tails, const float* __restrict__ icnt,
                           float* __restrict__ A0I, float* __restrict__ ER,
                           float* __restrict__ sn2) {
    if (blockIdx.x < UH_GRID) {
        int wid = (blockIdx.x * blockDim.x + threadIdx.x) >> 6;
        user_hop_body<true>(wid, A1, sn1, rowstart, cols, vals, UR, URI, nullptr);
    } else {
        int wid = (((blockIdx.x - UH_GRID) * blockDim.x) + threadIdx.x) >> 6;
        kg_hop_body<false>(wid, rowptr, tails, icnt, A1, A0I, ER, nullptr, sn2, N_ITEMS);
    }
}

// ==== fin: user_hop2 (+XH user part) || ER -> XH items cvt ====
__global__ void fin_kernel(const float* __restrict__ A0I, const float* __restrict__ sn2,
                           const int* __restrict__ rowstart, const int* __restrict__ cols,
                           const float* __restrict__ vals, float* __restrict__ UR,
                           f16* __restrict__ XH, const float* __restrict__ ER) {
    if (blockIdx.x < UH_GRID) {
        int wid = (blockIdx.x * blockDim.x + threadIdx.x) >> 6;
        user_hop_body<false>(wid, A0I, sn2, rowstart, cols, vals, UR, nullptr, XH);
    } else {
        int i = (blockIdx.x - UH_GRID) * blockDim.x + threadIdx.x;
        if (i < (N_ITEMS * D) / 4)
            st_h4(XH + (size_t)N_USERS * D + (size_t)i * 4,
                  *(const float4*)(ER + (size_t)i * 4));
    }
}

// ==== adj gather SpMM over fp16 rows, packed 4B (col,val); fp32 epilogues ====
__device__ __forceinline__ const float* xrow32(const float* U, const float* I, int c) {
    return (c < N_USERS) ? (U + (size_t)c * D) : (I + (size_t)(c - N_USERS) * D);
}

template <int MODE>
__global__ void adj_spmm(const int* __restrict__ rowptr, const int* __restrict__ pair,
                         const f16* __restrict__ X, const float* __restrict__ XAU,
                         const float* __restrict__ XAI, f16* __restrict__ Y,
                         float* __restrict__ out) {
    int wid = (blockIdx.x * blockDim.x + threadIdx.x) >> 6;
    int lane = threadIdx.x & 63;
    int g = lane >> 4, gl = lane & 15;
    if (wid >= N_UI) return;
    int s = rowptr[wid], t = rowptr[wid + 1];
    float4 acc = {0.f, 0.f, 0.f, 0.f};
    for (int e = s + g; e < t; e += 16) {
        int e1 = e + 4, e2 = e + 8, e3 = e + 12;
        int p0 = pair[e];
        int p1 = (e1 < t) ? pair[e1] : 0;
        int p2 = (e2 < t) ? pair[e2] : 0;
        int p3 = (e3 < t) ? pair[e3] : 0;
        float4 r0 = ld_h4(X + (size_t)((unsigned)p0 >> 15) * D + gl * 4);
        float4 r1 = {0.f, 0.f, 0.f, 0.f};
        float4 r2 = {0.f, 0.f, 0.f, 0.f};
        float4 r3 = {0.f, 0.f, 0.f, 0.f};
        if (e1 < t) r1 = ld_h4(X + (size_t)((unsigned)p1 >> 15) * D + gl * 4);
        if (e2 < t) r2 = ld_h4(X + (size_t)((unsigned)p2 >> 15) * D + gl * 4);
        if (e3 < t) r3 = ld_h4(X + (size_t)((unsigned)p3 >> 15) * D + gl * 4);
        float v0 = bits_f16(p0 & 0x7FFF), v1 = bits_f16(p1 & 0x7FFF);
        float v2 = bits_f16(p2 & 0x7FFF), v3 = bits_f16(p3 & 0x7FFF);
        acc.x += (v0 * r0.x + v1 * r1.x) + (v2 * r2.x + v3 * r3.x);
        acc.y += (v0 * r0.y + v1 * r1.y) + (v2 * r2.y + v3 * r3.y);
        acc.z += (v0 * r0.z + v1 * r1.z) + (v2 * r2.z + v3 * r3.z);
        acc.w += (v0 * r0.w + v1 * r1.w) + (v2 * r2.w + v3 * r3.w);
    }
    acc.x += __shfl_xor(acc.x, 16, 64); acc.x += __shfl_xor(acc.x, 32, 64);
    acc.y += __shfl_xor(acc.y, 16, 64); acc.y += __shfl_xor(acc.y, 32, 64);
    acc.z += __shfl_xor(acc.z, 16, 64); acc.z += __shfl_xor(acc.z, 32, 64);
    acc.w += __shfl_xor(acc.w, 16, 64); acc.w += __shfl_xor(acc.w, 32, 64);
    if (g == 0) {
        size_t o = (size_t)wid * D + gl * 4;
        if (MODE == 0) {
            st_h4(Y + o, acc);
            const float4 xa = *(const float4*)(xrow32(XAU, XAI, wid) + gl * 4);
            float4 ov = {xa.x + acc.x, xa.y + acc.y, xa.z + acc.z, xa.w + acc.w};
            *(float4*)(out + o) = ov;
        } else {
            float4 ov = *(const float4*)(out + o);
            ov.x = (ov.x + acc.x) * (1.0f / 3.0f);
            ov.y = (ov.y + acc.y) * (1.0f / 3.0f);
            ov.z = (ov.z + acc.z) * (1.0f / 3.0f);
            ov.w = (ov.w + acc.w) * (1.0f / 3.0f);
            *(float4*)(out + o) = ov;
        }
    }
}

extern "C" void kernel_launch(void* const* d_in, const int* in_sizes, int n_in,
                              void* d_out, int out_size, void* d_ws, size_t ws_size,
                              hipStream_t stream) {
    const float* all_embed     = (const float*)d_in[0];
    const float* interact_vals = (const float*)d_in[1];
    const float* adj_vals      = (const float*)d_in[2];
    const int*   edge_index    = (const int*)d_in[3];
    // d_in[4] = edge_type (unused)
    const int*   interact_rows = (const int*)d_in[5];
    const int*   interact_cols = (const int*)d_in[6];
    const int*   adj_rows      = (const int*)d_in[7];
    const int*   adj_cols      = (const int*)d_in[8];
    float* out = (float*)d_out;

    const size_t usrN = (size_t)N_USERS * D;      // 3,200,000
    const size_t itmN = (size_t)N_ITEMS * D;      // 1,920,000
    const size_t entN = (size_t)N_ENTITIES * D;   // 5,120,000

    float* cur = (float*)d_ws;
    float* UR  = cur; cur += usrN;                // u_res (KG_BIN overlays pre-mid)
    float* ER  = cur; cur += itmN;                // e_res items
    float* A0I = cur; cur += itmN;                // hop-2 output, items only
    float* A1  = cur; cur += entN;                // hop-1 output (rc pre / XH,X1H post)
    int*  KG_TAIL  = (int*)cur; cur += N_KG_EDGES;
    int*  ADJ_PAIR = (int*)cur; cur += N_ADJ;     // packed 4B (col<<15 | f16 bits)
    float* ICNT   = cur; cur += N_ENTITIES;
    float* SNORM1 = cur; cur += N_ITEMS + 16;
    float* SNORM2 = cur; cur += N_ITEMS + 16;
    int* KG_ROWPTR  = (int*)cur;                   // N_ENTITIES+1 (+pad)
    int* ADJ_ROWPTR = KG_ROWPTR + N_ENTITIES + 2;  // N_UI+1 (+pad)
    int* BCNT_K     = ADJ_ROWPTR + N_UI + 2;       // NB (K/A contiguous for memset)
    int* BCNT_A     = BCNT_K + NB;                 // NB
    int* BOFF_K     = BCNT_A + NB;                 // NB+1
    int* BOFF_A     = BOFF_K + NB + 1;             // NB+1
    int* BCUR_K     = BOFF_A + NB + 1;             // NB
    int* BCUR_A     = BCUR_K + NB;                 // NB
    int* ROWSTART   = BCUR_A + NB;                 // N_USERS+1

    // overlays (timeline-disjoint)
    int* KG_BIN = (int*)UR;                        // binA..binC, before user_hop1 writes UR
    int* ADJ_RCP = (int*)A1;                       // binA..binC, before kg1 writes A1
    u8*  ADJ_RCK = (u8*)(A1 + N_ADJ);              // 2 MB, after RCP's 8 MB
    f16* XH  = (f16*)A1;                           // after mid (A1 dead post kg_hop2)
    f16* X1H = XH + (size_t)N_UI * D;

    // ---- CSR builds (KG + adj fused stage-wise) ----
    hipMemsetAsync(BCNT_K, 0, 2 * NB * sizeof(int), stream);
    stageA<<<2 * GRID_EP + 49, BIG, 0, stream>>>(edge_index, adj_rows, interact_rows,
                                                 BCNT_K, BCNT_A, ROWSTART);
    bscan_both<<<2, 256, 0, stream>>>(BCNT_K, BOFF_K, BCUR_K, BCNT_A, BOFF_A, BCUR_A);
    binA_both<<<2 * GRID_EP, BIG, 0, stream>>>(edge_index, BCUR_K, KG_BIN, adj_rows,
                                               adj_cols, adj_vals, BCUR_A,
                                               ADJ_RCP, ADJ_RCK);
    binC_both<<<2 * NB, 256, 0, stream>>>(BOFF_K, KG_BIN, KG_TAIL, KG_ROWPTR, ICNT,
                                          BOFF_A, ADJ_RCP, ADJ_RCK, ADJ_PAIR,
                                          ADJ_ROWPTR);

    // ---- KG hops: kg1 -> (user1 || kg2) -> (user2 || cvt-items) ----
    kg1_kernel<<<N_ENTITIES / 4, 256, 0, stream>>>(KG_ROWPTR, KG_TAIL, ICNT,
                                                   all_embed + usrN, A1, ER,
                                                   all_embed + usrN, SNORM1);
    mid_kernel<<<UH_GRID + KG2_GRID, 256, 0, stream>>>(A1, SNORM1, ROWSTART,
                                                       interact_cols, interact_vals,
                                                       UR, all_embed, KG_ROWPTR, KG_TAIL,
                                                       ICNT, A0I, ER, SNORM2);
    fin_kernel<<<UH_GRID + CVT_GRID, 256, 0, stream>>>(A0I, SNORM2, ROWSTART,
                                                       interact_cols, interact_vals,
                                                       UR, XH, ER);

    // ---- LGCN: x1 = adj@x -> X1H(f16), out = x + x1; out = (out + adj@x1)/3 ----
    adj_spmm<0><<<N_UI / 4, 256, 0, stream>>>(ADJ_ROWPTR, ADJ_PAIR, XH, UR, ER, X1H, out);
    adj_spmm<1><<<N_UI / 4, 256, 0, stream>>>(ADJ_ROWPTR, ADJ_PAIR, X1H, nullptr, nullptr,
                                              nullptr, out);
}